// Round 6
// baseline (809.211 us; speedup 1.0000x reference)
//
#include <hip/hip_runtime.h>

#define NLEVELS 16
#define HSIZE (1u << 19)
#define HMASK ((1u << 19) - 1u)
#define P2 73856093u
#define P3 19349663u

// clang-native 16B vector (accepted by __builtin_nontemporal_*, unlike HIP float4)
typedef float nf4 __attribute__((ext_vector_type(4)));

// res[L] = floor(16 * (2^(1/3))^L)
__constant__ int c_res[NLEVELS] = {16, 20, 25, 32, 40, 50, 64, 80,
                                   101, 128, 161, 203, 256, 322, 406, 512};

// ---------------------------------------------------------------------------
// FUSED kernel (r6): point-major. Block = 256 points; loop over all 16 levels;
// per-level paired-corner 16B gathers (r4's proven 1.38x win, unchanged);
// results accumulate in an LDS tile [256][17]; final phase = the old
// transpose's coalesced 8x16B-per-thread write-out, now in-block.
// Eliminates: the invariant-175us transpose kernel, 256 MB of ws round-trip
// traffic, and 15 of 16 position passes (positions read ONCE, 12 MB).
// Level order rotates by XCD (start = (blockIdx&7)*2) so blocks on one XCD
// stream the same table together -> table stays L2-resident per phase;
// levels 0..6 have cumulative working set ~4 MB (always L2-hot), 7..15 are
// L3-served (all tables = 64 MB << 256 MB L3).
// ---------------------------------------------------------------------------
__global__ __launch_bounds__(256) void hashgrid_fused(
    const float* __restrict__ positions,  // [npoints, 3]
    const float* __restrict__ tables,     // [16, 2^19, 2]
    nf4* __restrict__ out4,               // [npoints][16] float2 = npoints*8 nf4
    int npoints)
{
    __shared__ float2 lds[256][NLEVELS + 1];   // +1 pad: write conflicts <=4-way
    const int c = blockIdx.x;
    const int t = threadIdx.x;
    const int p = (c << 8) + t;
    const bool valid = (p < npoints);

    // position -> [0,1]; two rounding steps match reference exactly
    float px = 0.0f, py = 0.0f, pz = 0.0f;
    if (valid) {
        px = (positions[3 * p + 0] + 1.0f) * 0.5f;
        py = (positions[3 * p + 1] + 1.0f) * 0.5f;
        pz = (positions[3 * p + 2] + 1.0f) * 0.5f;
    }
    // invalid lanes: px=py=pz=0 -> hashed addresses still in-bounds, harmless.

    const int Lbase = (c & 7) << 1;   // XCD-rotated level start

#pragma unroll
    for (int it = 0; it < NLEVELS; ++it) {
        const int L = (Lbase + it) & (NLEVELS - 1);
        const float rm1 = (float)(c_res[L] - 1);
        float sx = px * rm1, sy = py * rm1, sz = pz * rm1;
        float bx = floorf(sx), by = floorf(sy), bz = floorf(sz);
        float fx = sx - bx, fy = sy - by, fz = sz - bz;

        unsigned ix = (unsigned)(int)bx;
        unsigned iy = (unsigned)(int)by;
        unsigned iz = (unsigned)(int)bz;

        unsigned s00 = ix + iy * P2 + iz * P3;
        // pair k covers corners (x=0, x=1) at (dy,dz) = (0,0),(1,0),(0,1),(1,1)
        unsigned hl0 = s00 & HMASK;
        unsigned hl1 = (s00 + P2) & HMASK;
        unsigned hl2 = (s00 + P3) & HMASK;
        unsigned hl3 = (s00 + P2 + P3) & HMASK;

        const float* tabf = tables + (size_t)L * (2u * HSIZE);
        float2 t0 = ((const float2*)tabf)[0];      // wave-uniform wrap partner

        unsigned w0 = (hl0 == HMASK) ? 1u : 0u;
        unsigned w1 = (hl1 == HMASK) ? 1u : 0u;
        unsigned w2 = (hl2 == HMASK) ? 1u : 0u;
        unsigned w3 = (hl3 == HMASK) ? 1u : 0u;

        // 16B paired loads: entries {h-w, h-w+1}. All 4 independent.
        nf4 g0 = *(const nf4*)(tabf + 2u * (hl0 - w0));
        nf4 g1 = *(const nf4*)(tabf + 2u * (hl1 - w1));
        nf4 g2 = *(const nf4*)(tabf + 2u * (hl2 - w2));
        nf4 g3 = *(const nf4*)(tabf + 2u * (hl3 - w3));

        // lo corner = entry h, hi corner = entry (h+1)&HMASK
        float l0x = w0 ? g0.z : g0.x, l0y = w0 ? g0.w : g0.y;
        float h0x = w0 ? t0.x : g0.z, h0y = w0 ? t0.y : g0.w;
        float l1x = w1 ? g1.z : g1.x, l1y = w1 ? g1.w : g1.y;
        float h1x = w1 ? t0.x : g1.z, h1y = w1 ? t0.y : g1.w;
        float l2x = w2 ? g2.z : g2.x, l2y = w2 ? g2.w : g2.y;
        float h2x = w2 ? t0.x : g2.z, h2y = w2 ? t0.y : g2.w;
        float l3x = w3 ? g3.z : g3.x, l3y = w3 ? g3.w : g3.y;
        float h3x = w3 ? t0.x : g3.z, h3y = w3 ? t0.y : g3.w;

        float wx0 = 1.0f - fx, wy0 = 1.0f - fy, wz0 = 1.0f - fz;
        float c0 = wy0 * wz0;   // (dy,dz)=(0,0)
        float c1 = fy * wz0;    // (1,0)
        float c2 = wy0 * fz;    // (0,1)
        float c3 = fy * fz;     // (1,1)

        float o0 = c0 * (wx0 * l0x + fx * h0x)
                 + c1 * (wx0 * l1x + fx * h1x)
                 + c2 * (wx0 * l2x + fx * h2x)
                 + c3 * (wx0 * l3x + fx * h3x);
        float o1 = c0 * (wx0 * l0y + fx * h0y)
                 + c1 * (wx0 * l1y + fx * h1y)
                 + c2 * (wx0 * l2y + fx * h2y)
                 + c3 * (wx0 * l3y + fx * h3y);

        lds[t][L] = make_float2(o0, o1);
    }

    __syncthreads();

    // write-out: tile is [256 points][16 levels] float2 = 2048 nf4, contiguous
    // in out. Thread handles 8 nf4; each wave stores 1 KB contiguous (nt).
    const size_t base = (size_t)c * 2048;
#pragma unroll
    for (int k = 0; k < 8; ++k) {
        int i = (k << 8) + t;
        int pp = i >> 3;                  // point within tile
        int q = i & 7;                    // level pair
        if ((c << 8) + pp < npoints) {
            float2 a = lds[pp][2 * q];
            float2 b = lds[pp][2 * q + 1];
            nf4 v = {a.x, a.y, b.x, b.y};
            __builtin_nontemporal_store(v, &out4[base + i]);
        }
    }
}

extern "C" void kernel_launch(void* const* d_in, const int* in_sizes, int n_in,
                              void* d_out, int out_size, void* d_ws, size_t ws_size,
                              hipStream_t stream) {
    const float* positions = (const float*)d_in[0];
    const float* tables = (const float*)d_in[1];
    int npoints = in_sizes[0] / 3;            // 1,048,576
    int blocks = (npoints + 255) >> 8;        // 4096
    hashgrid_fused<<<blocks, 256, 0, stream>>>(positions, tables,
                                               (nf4*)d_out, npoints);
}

// Round 7
// 509.339 us; speedup vs baseline: 1.5887x; 1.5887x over previous
//
#include <hip/hip_runtime.h>

#define NLEVELS 16
#define HSIZE (1u << 19)
#define HMASK ((1u << 19) - 1u)
#define P2 73856093u
#define P3 19349663u

// clang-native vectors (accepted by __builtin_nontemporal_*, unlike HIP types)
typedef float nf4 __attribute__((ext_vector_type(4)));
typedef float nf2 __attribute__((ext_vector_type(2)));

// res[L] = floor(16 * (2^(1/3))^L)
__constant__ int c_res[NLEVELS] = {16, 20, 25, 32, 40, 50, 64, 80,
                                   101, 128, 161, 203, 256, 322, 406, 512};

// ---------------------------------------------------------------------------
// Kernel A (r7): r5 level-major structure (best verified) + FORCED-PARALLEL
// gathers. r0/r4/r5 all compiled to VGPR_Count=20 -> the allocator reused one
// destination quad and SERIALIZED the 4 paired gathers (4 sequential ~400cyc
// L2 round-trips per wave; explains idle pipes + why r2's unroll hurt).
// The empty asm keep-alive after all four loads forces all four destinations
// live at once -> 4 back-to-back global_load_dwordx4, one waitcnt.
// ---------------------------------------------------------------------------
template <bool TO_WS>
__global__ __launch_bounds__(256) void hashgrid_kernel(
    const float* __restrict__ positions,  // [npoints, 3]
    const float* __restrict__ tables,     // [16, 2^19, 2]
    float2* __restrict__ dst,             // TO_WS: tiled ws; else out [npoints][16]
    int npoints)
{
    int nch = (npoints + 255) >> 8;       // 256-point chunks
    int b = blockIdx.x;
    int L, chunk;
    if (TO_WS) {
        int xcd = b & 7;
        int j = b >> 3;                   // [0, 2*nch)
        L = xcd + ((j >= nch) ? 8 : 0);
        chunk = (j >= nch) ? (j - nch) : j;
    } else {
        L = b / nch;
        chunk = b - L * nch;
    }
    int p = (chunk << 8) + threadIdx.x;
    if (p >= npoints) return;

    float px = (positions[3 * p + 0] + 1.0f) * 0.5f;
    float py = (positions[3 * p + 1] + 1.0f) * 0.5f;
    float pz = (positions[3 * p + 2] + 1.0f) * 0.5f;

    float rm1 = (float)(c_res[L] - 1);
    float sx = px * rm1, sy = py * rm1, sz = pz * rm1;
    float bx = floorf(sx), by = floorf(sy), bz = floorf(sz);
    float fx = sx - bx, fy = sy - by, fz = sz - bz;

    unsigned ix = (unsigned)(int)bx;
    unsigned iy = (unsigned)(int)by;
    unsigned iz = (unsigned)(int)bz;

    unsigned s00 = ix + iy * P2 + iz * P3;
    // pair k covers corners (x=0, x=1) at (dy,dz) = (0,0),(1,0),(0,1),(1,1)
    unsigned hl0 = s00 & HMASK;
    unsigned hl1 = (s00 + P2) & HMASK;
    unsigned hl2 = (s00 + P3) & HMASK;
    unsigned hl3 = (s00 + P2 + P3) & HMASK;

    const float* tabf = tables + (size_t)L * (2u * HSIZE);

    unsigned w0 = (hl0 == HMASK) ? 1u : 0u;
    unsigned w1 = (hl1 == HMASK) ? 1u : 0u;
    unsigned w2 = (hl2 == HMASK) ? 1u : 0u;
    unsigned w3 = (hl3 == HMASK) ? 1u : 0u;

    // 16B paired loads: entries {h-w, h-w+1}. Issue ALL FOUR, then force all
    // destinations live (keep-alive) so the allocator cannot serialize them.
    nf4 g0 = *(const nf4*)(tabf + 2u * (hl0 - w0));
    nf4 g1 = *(const nf4*)(tabf + 2u * (hl1 - w1));
    nf4 g2 = *(const nf4*)(tabf + 2u * (hl2 - w2));
    nf4 g3 = *(const nf4*)(tabf + 2u * (hl3 - w3));
    asm volatile("" :: "v"(g0), "v"(g1), "v"(g2), "v"(g3));

    float2 t0 = ((const float2*)tabf)[0];         // wave-uniform wrap partner

    // lo corner = entry h, hi corner = entry (h+1)&HMASK
    float l0x = w0 ? g0.z : g0.x, l0y = w0 ? g0.w : g0.y;
    float h0x = w0 ? t0.x : g0.z, h0y = w0 ? t0.y : g0.w;
    float l1x = w1 ? g1.z : g1.x, l1y = w1 ? g1.w : g1.y;
    float h1x = w1 ? t0.x : g1.z, h1y = w1 ? t0.y : g1.w;
    float l2x = w2 ? g2.z : g2.x, l2y = w2 ? g2.w : g2.y;
    float h2x = w2 ? t0.x : g2.z, h2y = w2 ? t0.y : g2.w;
    float l3x = w3 ? g3.z : g3.x, l3y = w3 ? g3.w : g3.y;
    float h3x = w3 ? t0.x : g3.z, h3y = w3 ? t0.y : g3.w;

    float wx0 = 1.0f - fx, wy0 = 1.0f - fy, wz0 = 1.0f - fz;
    float c0 = wy0 * wz0;   // (dy,dz)=(0,0)
    float c1 = fy * wz0;    // (1,0)
    float c2 = wy0 * fz;    // (0,1)
    float c3 = fy * fz;     // (1,1)

    float o0 = c0 * (wx0 * l0x + fx * h0x)
             + c1 * (wx0 * l1x + fx * h1x)
             + c2 * (wx0 * l2x + fx * h2x)
             + c3 * (wx0 * l3x + fx * h3x);
    float o1 = c0 * (wx0 * l0y + fx * h0y)
             + c1 * (wx0 * l1y + fx * h1y)
             + c2 * (wx0 * l2y + fx * h2y)
             + c3 * (wx0 * l3y + fx * h3y);

    if (TO_WS) {
        // tiled ws: f2 index = ((p>>8)*16 + L)*256 + (p&255); coalesced, nt.
        nf2 v = {o0, o1};
        __builtin_nontemporal_store(
            v, (nf2*)dst + ((size_t)chunk * NLEVELS + L) * 256 + threadIdx.x);
    } else {
        dst[(size_t)p * NLEVELS + L] = make_float2(o0, o1);
    }
}

// ---------------------------------------------------------------------------
// Kernel B (r7): tile transpose, with phase-1's 8 loads forced concurrent via
// the same keep-alive device (load->LDS chain was serial per thread at only
// 4 blocks/CU -> latency-bound).
// ---------------------------------------------------------------------------
__global__ __launch_bounds__(256) void transpose_kernel(
    const nf4* __restrict__ ws4,
    nf4* __restrict__ out4,
    int npoints)
{
    __shared__ float2 lds[256][NLEVELS + 1];
    int c = blockIdx.x;
    int t = threadIdx.x;
    size_t base = (size_t)c * 2048;   // 2048 x 16B per tile

    nf4 v0 = __builtin_nontemporal_load(&ws4[base + 0 * 256 + t]);
    nf4 v1 = __builtin_nontemporal_load(&ws4[base + 1 * 256 + t]);
    nf4 v2 = __builtin_nontemporal_load(&ws4[base + 2 * 256 + t]);
    nf4 v3 = __builtin_nontemporal_load(&ws4[base + 3 * 256 + t]);
    nf4 v4 = __builtin_nontemporal_load(&ws4[base + 4 * 256 + t]);
    nf4 v5 = __builtin_nontemporal_load(&ws4[base + 5 * 256 + t]);
    nf4 v6 = __builtin_nontemporal_load(&ws4[base + 6 * 256 + t]);
    nf4 v7 = __builtin_nontemporal_load(&ws4[base + 7 * 256 + t]);
    asm volatile("" :: "v"(v0), "v"(v1), "v"(v2), "v"(v3),
                       "v"(v4), "v"(v5), "v"(v6), "v"(v7));

    nf4 vv[8] = {v0, v1, v2, v3, v4, v5, v6, v7};
#pragma unroll
    for (int k = 0; k < 8; ++k) {
        int i = (k << 8) + t;                 // 16B covers f2 {2i, 2i+1}
        int L = i >> 7;                       // level
        int m = i & 127;                      // pts 2m, 2m+1
        lds[m][L]       = make_float2(vv[k].x, vv[k].y);   // row(2m)   = m
        lds[m + 128][L] = make_float2(vv[k].z, vv[k].w);   // row(2m+1) = m+128
    }
    __syncthreads();

#pragma unroll
    for (int k = 0; k < 8; ++k) {
        int i = (k << 8) + t;
        int pp = i >> 3;                      // point within tile
        int q = i & 7;                        // level pair
        int r = (pp >> 1) | ((pp & 1) << 7);  // physical row of point pp
        float2 a = lds[r][2 * q];
        float2 bb = lds[r][2 * q + 1];
        nf4 v = {a.x, a.y, bb.x, bb.y};
        __builtin_nontemporal_store(v, &out4[base + i]);
    }
}

extern "C" void kernel_launch(void* const* d_in, const int* in_sizes, int n_in,
                              void* d_out, int out_size, void* d_ws, size_t ws_size,
                              hipStream_t stream) {
    const float* positions = (const float*)d_in[0];
    const float* tables = (const float*)d_in[1];
    int npoints = in_sizes[0] / 3;                    // 1,048,576
    int nch = (npoints + 255) >> 8;
    int blocks = NLEVELS * nch;                       // 65,536

    size_t ws_needed = (size_t)NLEVELS * npoints * sizeof(float2);  // 128 MiB
    if (ws_size >= ws_needed && (npoints & 255) == 0) {
        float2* ws = (float2*)d_ws;
        hashgrid_kernel<true><<<blocks, 256, 0, stream>>>(positions, tables, ws, npoints);
        transpose_kernel<<<npoints / 256, 256, 0, stream>>>((const nf4*)ws,
                                                            (nf4*)d_out, npoints);
    } else {
        hashgrid_kernel<false><<<blocks, 256, 0, stream>>>(positions, tables,
                                                           (float2*)d_out, npoints);
    }
}